// Round 1
// baseline (950.167 us; speedup 1.0000x reference)
//
#include <hip/hip_runtime.h>

typedef unsigned short u16;
typedef short s16x8 __attribute__((ext_vector_type(8)));
typedef float f32x4 __attribute__((ext_vector_type(4)));
typedef const __attribute__((address_space(1))) unsigned int* as1_u32p;
typedef __attribute__((address_space(3))) unsigned int* as3_u32p;

static_assert(sizeof(s16x8) == 16, "");

struct alignas(8) U16x4 { u16 x, y, z, w; };

__device__ __forceinline__ u16 f2bf(float f) {
  union { float f; unsigned u; } c; c.f = f;
  return (u16)((c.u + 0x7fffu + ((c.u >> 16) & 1u)) >> 16);
}
__device__ __forceinline__ float bf2f(u16 h) {
  union { unsigned u; float f; } c; c.u = ((unsigned)h) << 16;
  return c.f;
}
__device__ __forceinline__ void async16(const void* g, void* l) {
  __builtin_amdgcn_global_load_lds((as1_u32p)g, (as3_u32p)l, 16, 0, 0);
}

// ---------------- fp32 -> bf16 flat convert ----------------
__launch_bounds__(256)
__global__ void cvt_bf16(const float* __restrict__ in, u16* __restrict__ out, long n) {
  long i = ((long)blockIdx.x * 256 + threadIdx.x) * 8;
  if (i >= n) return;
  float4 a = *(const float4*)(in + i);
  float4 b = *(const float4*)(in + i + 4);
  U16x4 o0{f2bf(a.x), f2bf(a.y), f2bf(a.z), f2bf(a.w)};
  U16x4 o1{f2bf(b.x), f2bf(b.y), f2bf(b.z), f2bf(b.w)};
  *(U16x4*)(out + i) = o0;
  *(U16x4*)(out + i + 4) = o1;
}

// ---------------- pack 3 biases into one 9216 vector ----------------
__launch_bounds__(256)
__global__ void pack_bias(const float* __restrict__ a, const float* __restrict__ b,
                          const float* __restrict__ c, float* __restrict__ out) {
  int i = blockIdx.x * 256 + threadIdx.x;
  if (i >= 9216) return;
  out[i] = (i < 3072) ? a[i] : (i < 6144) ? b[i - 3072] : c[i - 6144];
}

// ---------------- weight transpose: W(K=3072,N=3072) f32 -> W^T(N,K) bf16 ----------------
struct WTArgs { const float* src[3]; u16* dst[3]; };

__launch_bounds__(256)
__global__ void transpose_w(WTArgs args) {
  const float* src = args.src[blockIdx.z];
  u16* dst = args.dst[blockIdx.z];
  __shared__ float tile[32][33];
  int k0 = blockIdx.x * 32, n0 = blockIdx.y * 32;
  int r = threadIdx.x >> 3, c4 = (threadIdx.x & 7) * 4;
  float4 v = *(const float4*)(src + (long)(k0 + r) * 3072 + n0 + c4);
  tile[r][c4 + 0] = v.x; tile[r][c4 + 1] = v.y;
  tile[r][c4 + 2] = v.z; tile[r][c4 + 3] = v.w;
  __syncthreads();
  U16x4 o{f2bf(tile[c4 + 0][r]), f2bf(tile[c4 + 1][r]),
          f2bf(tile[c4 + 2][r]), f2bf(tile[c4 + 3][r])};
  *(U16x4*)(dst + (long)(n0 + r) * 3072 + k0 + c4) = o;
}

// ---------------- bf16 head transpose (T,128)->(128,T) per head ----------------
__launch_bounds__(256)
__global__ void transpose_v(const u16* __restrict__ VB, u16* __restrict__ VT, int T) {
  __shared__ u16 tile[32][34];
  int h = blockIdx.z;
  int t0 = blockIdx.x * 32, d0 = blockIdx.y * 32;
  int r = threadIdx.x >> 3, c4 = (threadIdx.x & 7) * 4;
  U16x4 v = *(const U16x4*)(VB + ((long)h * T + t0 + r) * 128 + d0 + c4);
  tile[r][c4 + 0] = v.x; tile[r][c4 + 1] = v.y;
  tile[r][c4 + 2] = v.z; tile[r][c4 + 3] = v.w;
  __syncthreads();
  U16x4 o{tile[c4 + 0][r], tile[c4 + 1][r], tile[c4 + 2][r], tile[c4 + 3][r]};
  *(U16x4*)(VT + ((long)h * 128 + d0 + r) * T + t0 + c4) = o;
}

// ---------------- RMS + to_heads (or plain convert) ----------------
// in: (T, ldin) fp32 (already column-offset).  out: (24, OT, 128) bf16 at row t0+t.
__launch_bounds__(256)
__global__ void rms_heads(const float* __restrict__ in, int ldin,
                          u16* __restrict__ out, int OT, int t0, int do_rms) {
  const int t = blockIdx.x;
  const int w = threadIdx.x >> 6, lane = threadIdx.x & 63;
#pragma unroll
  for (int hh = 0; hh < 6; ++hh) {
    int h = w * 6 + hh;
    const float* x = in + (long)t * ldin + h * 128 + lane * 2;
    float a = x[0], b = x[1];
    float scale = 1.f;
    if (do_rms) {
      float ss = a * a + b * b;
#pragma unroll
      for (int st = 1; st < 64; st <<= 1) ss += __shfl_xor(ss, st, 64);
      scale = rsqrtf(ss * (1.f / 128.f) + 1e-5f);
    }
    unsigned pa = f2bf(a * scale), pb = f2bf(b * scale);
    *(unsigned*)(out + ((long)h * OT + t0 + t) * 128 + lane * 2) = pa | (pb << 16);
  }
}

// ---------------- LoRA ----------------
// t[m][r] = sum_k X[m][k] * dn[k][r]   (M=1024 blocks, K=3072, R=16)
__launch_bounds__(256)
__global__ void lora_dn(const float* __restrict__ X, int ldx,
                        const float* __restrict__ dn, float* __restrict__ t) {
  __shared__ float red[4][16];
  const int m = blockIdx.x;
  const float* xr = X + (long)m * ldx;
  float p[16];
#pragma unroll
  for (int r = 0; r < 16; ++r) p[r] = 0.f;
  for (int k = threadIdx.x; k < 3072; k += 256) {
    float a = xr[k];
    const float* d = dn + (long)k * 16;
#pragma unroll
    for (int r = 0; r < 16; ++r) p[r] += a * d[r];
  }
#pragma unroll
  for (int r = 0; r < 16; ++r)
#pragma unroll
    for (int st = 1; st < 64; st <<= 1) p[r] += __shfl_xor(p[r], st, 64);
  int lane = threadIdx.x & 63, w = threadIdx.x >> 6;
  if (lane == 0) {
#pragma unroll
    for (int r = 0; r < 16; ++r) red[w][r] = p[r];
  }
  __syncthreads();
  if (threadIdx.x < 16) {
    int r = threadIdx.x;
    t[(long)m * 16 + r] = red[0][r] + red[1][r] + red[2][r] + red[3][r];
  }
}

// Y[m][n] += sum_r t[m][r]*up[r][n]
__launch_bounds__(256)
__global__ void lora_up(const float* __restrict__ t, const float* __restrict__ up,
                        float* __restrict__ Y, int ldy) {
  const int m = blockIdx.x;
  float tv[16];
#pragma unroll
  for (int r = 0; r < 16; ++r) tv[r] = t[(long)m * 16 + r];
  float* yr = Y + (long)m * ldy;
  for (int n = threadIdx.x; n < 3072; n += 256) {
    float a = 0.f;
#pragma unroll
    for (int r = 0; r < 16; ++r) a += tv[r] * up[(long)r * 3072 + n];
    yr[n] += a;
  }
}

// ---------------- GEMM: C(M,N) f32 = A(M,K)bf16 @ B^T(N,K)bf16 + bias ----------------
// 256 threads = 4 waves; BM x 128 tile; BK=64; XOR-swizzled LDS; global_load_lds staging.
template <int BM, int MI, int NI>
__launch_bounds__(256)
__global__ void gemm_bf16(const u16* __restrict__ A, int lda,
                          const u16* __restrict__ B, int ldb,
                          float* __restrict__ C, int ldc,
                          const float* __restrict__ bias, int K) {
  constexpr int WCOLS = 128 / (NI * 16);
  constexpr int ABYTES = BM * 128;  // BM rows x 64 k x 2B
  __shared__ char smem[ABYTES + 128 * 128];
  char* As = smem;
  char* Bs = smem + ABYTES;
  const int tid = threadIdx.x;
  const int w = tid >> 6, lane = tid & 63;
  const int lr = lane & 15, lg = lane >> 4;
  const int wr = w / WCOLS, wc = w % WCOLS;
  const long m0 = (long)blockIdx.x * BM;
  const long n0 = (long)blockIdx.y * 128;
  f32x4 acc[MI][NI] = {};
  constexpr int ACH = BM / 32;
  for (int kb = 0; kb < K; kb += 64) {
    __syncthreads();
#pragma unroll
    for (int i = 0; i < ACH; ++i) {
      int x = (tid + 256 * i) * 16;
      int row = x >> 7;
      int sx = x ^ ((row & 7) << 4);
      async16((const char*)(A + (m0 + row) * lda + kb) + (sx & 127),
              As + ((w << 10) + (i << 12)));
    }
#pragma unroll
    for (int i = 0; i < 4; ++i) {
      int x = (tid + 256 * i) * 16;
      int row = x >> 7;
      int sx = x ^ ((row & 7) << 4);
      async16((const char*)(B + (n0 + row) * ldb + kb) + (sx & 127),
              Bs + ((w << 10) + (i << 12)));
    }
    __syncthreads();
#pragma unroll
    for (int kc = 0; kc < 2; ++kc) {
      s16x8 af[MI], bfr[NI];
#pragma unroll
      for (int mi = 0; mi < MI; ++mi) {
        int row = wr * (MI * 16) + mi * 16 + lr;
        int b = ((row << 7) + kc * 64 + lg * 16) ^ ((row & 7) << 4);
        af[mi] = *(const s16x8*)(As + b);
      }
#pragma unroll
      for (int ni = 0; ni < NI; ++ni) {
        int row = wc * (NI * 16) + ni * 16 + lr;
        int b = ((row << 7) + kc * 64 + lg * 16) ^ ((row & 7) << 4);
        bfr[ni] = *(const s16x8*)(Bs + b);
      }
#pragma unroll
      for (int mi = 0; mi < MI; ++mi)
#pragma unroll
        for (int ni = 0; ni < NI; ++ni)
          acc[mi][ni] = __builtin_amdgcn_mfma_f32_16x16x32_bf16(af[mi], bfr[ni], acc[mi][ni], 0, 0, 0);
    }
  }
#pragma unroll
  for (int mi = 0; mi < MI; ++mi) {
#pragma unroll
    for (int ni = 0; ni < NI; ++ni) {
      long col = n0 + wc * (NI * 16) + ni * 16 + lr;
      float bv = bias ? bias[col] : 0.f;
#pragma unroll
      for (int j = 0; j < 4; ++j) {
        long row = m0 + wr * (MI * 16) + mi * 16 + lg * 4 + j;
        C[row * ldc + col] = acc[mi][ni][j] + bv;
      }
    }
  }
}

// ---------------- main masked attention ----------------
// Q,K: (24,2560,128) bf16; VT: (24,128,2560) bf16; OutTok: (2560,3072) bf16.
// 4 waves x 16 queries = 64 q/block; KV tiles of 64 with online softmax.
__launch_bounds__(256)
__global__ void attn_main(const u16* __restrict__ QB, const u16* __restrict__ KB,
                          const u16* __restrict__ VT, u16* __restrict__ OutTok) {
  __shared__ char smem[40960];
  char* Ks = smem;
  char* Vs = smem + 16384;
  char* Ps = smem + 32768;
  const int tid = threadIdx.x, w = tid >> 6, lane = tid & 63;
  const int lr = lane & 15, lg = lane >> 4;
  const int h = blockIdx.y;
  const int q0 = blockIdx.x * 64;
  const u16* Qrow = QB + (long)(h * 2560 + q0 + w * 16 + lr) * 128;
  s16x8 qf[4];
#pragma unroll
  for (int dc = 0; dc < 4; ++dc) qf[dc] = *(const s16x8*)(Qrow + dc * 32 + lg * 8);
  f32x4 accO[8] = {};
  float m_r[4] = {-1e30f, -1e30f, -1e30f, -1e30f};
  float l_r[4] = {0.f, 0.f, 0.f, 0.f};
  const int kv0 = (q0 >= 1536) ? 1536 : 0;
  const float sc = 0.08838834764831845f;
  for (int kv = kv0; kv < 2560; kv += 64) {
    __syncthreads();
#pragma unroll
    for (int i = 0; i < 4; ++i) {  // K tile: 64 rows x 256B
      int x = (tid + 256 * i) * 16;
      int row = x >> 8;
      int sx = x ^ ((row & 7) << 4);
      async16((const char*)(KB + (long)(h * 2560 + kv + row) * 128) + (sx & 255),
              Ks + ((w << 10) + (i << 12)));
    }
#pragma unroll
    for (int i = 0; i < 4; ++i) {  // V^T tile: 128 rows x 128B
      int x = (tid + 256 * i) * 16;
      int row = x >> 7;
      int sx = x ^ ((row & 7) << 4);
      async16((const char*)(VT + (long)(h * 128 + row) * 2560 + kv) + (sx & 127),
              Vs + ((w << 10) + (i << 12)));
    }
    __syncthreads();
    f32x4 s[4] = {};
#pragma unroll
    for (int kt = 0; kt < 4; ++kt)
#pragma unroll
      for (int dc = 0; dc < 4; ++dc) {
        int row = kt * 16 + lr;
        int b = ((row << 8) + dc * 64 + lg * 16) ^ ((row & 7) << 4);
        s16x8 kf = *(const s16x8*)(Ks + b);
        s[kt] = __builtin_amdgcn_mfma_f32_16x16x32_bf16(qf[dc], kf, s[kt], 0, 0, 0);
      }
    float mn[4], f[4], rs[4], p[4][4];
#pragma unroll
    for (int j = 0; j < 4; ++j) {
      float v = fmaxf(fmaxf(s[0][j], s[1][j]), fmaxf(s[2][j], s[3][j]));
#pragma unroll
      for (int st = 1; st < 16; st <<= 1) v = fmaxf(v, __shfl_xor(v, st, 16));
      mn[j] = v * sc;
      float m2 = fmaxf(m_r[j], mn[j]);
      f[j] = __expf(m_r[j] - m2);
      m_r[j] = m2;
      rs[j] = 0.f;
    }
#pragma unroll
    for (int kt = 0; kt < 4; ++kt)
#pragma unroll
      for (int j = 0; j < 4; ++j) {
        float pv = __expf(s[kt][j] * sc - m_r[j]);
        p[kt][j] = pv;
        rs[j] += pv;
      }
#pragma unroll
    for (int j = 0; j < 4; ++j) {
#pragma unroll
      for (int st = 1; st < 16; st <<= 1) rs[j] += __shfl_xor(rs[j], st, 16);
      l_r[j] = l_r[j] * f[j] + rs[j];
    }
#pragma unroll
    for (int dt = 0; dt < 8; ++dt)
#pragma unroll
      for (int j = 0; j < 4; ++j) accO[dt][j] *= f[j];
    char* Pw = Ps + w * 2048;
#pragma unroll
    for (int kt = 0; kt < 4; ++kt)
#pragma unroll
      for (int j = 0; j < 4; ++j) {
        int row = lg * 4 + j;
        int b = ((row << 7) + (kt * 16 + lr) * 2) ^ ((row & 7) << 4);
        *(u16*)(Pw + b) = f2bf(p[kt][j]);
      }
    asm volatile("s_waitcnt lgkmcnt(0)" ::: "memory");
#pragma unroll
    for (int kc = 0; kc < 2; ++kc) {
      int pb = ((lr << 7) + kc * 64 + lg * 16) ^ ((lr & 7) << 4);
      s16x8 pf = *(const s16x8*)(Pw + pb);
#pragma unroll
      for (int dt = 0; dt < 8; ++dt) {
        int row = dt * 16 + lr;
        int b = ((row << 7) + kc * 64 + lg * 16) ^ ((row & 7) << 4);
        s16x8 vf = *(const s16x8*)(Vs + b);
        accO[dt] = __builtin_amdgcn_mfma_f32_16x16x32_bf16(pf, vf, accO[dt], 0, 0, 0);
      }
    }
  }
#pragma unroll
  for (int j = 0; j < 4; ++j) {
    float inv = 1.f / l_r[j];
    long tok = q0 + w * 16 + lg * 4 + j;
#pragma unroll
    for (int dt = 0; dt < 8; ++dt) {
      long col = h * 128 + dt * 16 + lr;
      OutTok[tok * 3072 + col] = f2bf(accO[dt][j] * inv);
    }
  }
}

// ---------------- IP attention (64 keys, no mask), adds into OutTok rows 512.. ----------------
__launch_bounds__(256)
__global__ void attn_ip(const u16* __restrict__ QB, const u16* __restrict__ KipB,
                        const u16* __restrict__ VipT, u16* __restrict__ OutTok) {
  __shared__ char smem[40960];
  char* Ks = smem;
  char* Vs = smem + 16384;
  char* Ps = smem + 32768;
  const int tid = threadIdx.x, w = tid >> 6, lane = tid & 63;
  const int lr = lane & 15, lg = lane >> 4;
  const int h = blockIdx.y;
  const int q0 = blockIdx.x * 64;
  const u16* Qrow = QB + (long)(h * 2560 + 512 + q0 + w * 16 + lr) * 128;
  s16x8 qf[4];
#pragma unroll
  for (int dc = 0; dc < 4; ++dc) qf[dc] = *(const s16x8*)(Qrow + dc * 32 + lg * 8);
#pragma unroll
  for (int i = 0; i < 4; ++i) {
    int x = (tid + 256 * i) * 16;
    int row = x >> 8;
    int sx = x ^ ((row & 7) << 4);
    async16((const char*)(KipB + (long)(h * 64 + row) * 128) + (sx & 255),
            Ks + ((w << 10) + (i << 12)));
  }
#pragma unroll
  for (int i = 0; i < 4; ++i) {
    int x = (tid + 256 * i) * 16;
    int row = x >> 7;
    int sx = x ^ ((row & 7) << 4);
    async16((const char*)(VipT + (long)(h * 128 + row) * 64) + (sx & 127),
            Vs + ((w << 10) + (i << 12)));
  }
  __syncthreads();
  const float sc = 0.08838834764831845f;
  f32x4 s[4] = {};
#pragma unroll
  for (int kt = 0; kt < 4; ++kt)
#pragma unroll
    for (int dc = 0; dc < 4; ++dc) {
      int row = kt * 16 + lr;
      int b = ((row << 8) + dc * 64 + lg * 16) ^ ((row & 7) << 4);
      s16x8 kf = *(const s16x8*)(Ks + b);
      s[kt] = __builtin_amdgcn_mfma_f32_16x16x32_bf16(qf[dc], kf, s[kt], 0, 0, 0);
    }
  float m[4], l[4], p[4][4];
#pragma unroll
  for (int j = 0; j < 4; ++j) {
    float v = fmaxf(fmaxf(s[0][j], s[1][j]), fmaxf(s[2][j], s[3][j]));
#pragma unroll
    for (int st = 1; st < 16; st <<= 1) v = fmaxf(v, __shfl_xor(v, st, 16));
    m[j] = v * sc;
    l[j] = 0.f;
  }
#pragma unroll
  for (int kt = 0; kt < 4; ++kt)
#pragma unroll
    for (int j = 0; j < 4; ++j) {
      float pv = __expf(s[kt][j] * sc - m[j]);
      p[kt][j] = pv;
      l[j] += pv;
    }
#pragma unroll
  for (int j = 0; j < 4; ++j)
#pragma unroll
    for (int st = 1; st < 16; st <<= 1) l[j] += __shfl_xor(l[j], st, 16);
  char* Pw = Ps + w * 2048;
#pragma unroll
  for (int kt = 0; kt < 4; ++kt)
#pragma unroll
    for (int j = 0; j < 4; ++j) {
      int row = lg * 4 + j;
      int b = ((row << 7) + (kt * 16 + lr) * 2) ^ ((row & 7) << 4);
      *(u16*)(Pw + b) = f2bf(p[kt][j]);
    }
  asm volatile("s_waitcnt lgkmcnt(0)" ::: "memory");
  f32x4 accO[8] = {};
#pragma unroll
  for (int kc = 0; kc < 2; ++kc) {
    int pb = ((lr << 7) + kc * 64 + lg * 16) ^ ((lr & 7) << 4);
    s16x8 pf = *(const s16x8*)(Pw + pb);
#pragma unroll
    for (int dt = 0; dt < 8; ++dt) {
      int row = dt * 16 + lr;
      int b = ((row << 7) + kc * 64 + lg * 16) ^ ((row & 7) << 4);
      s16x8 vf = *(const s16x8*)(Vs + b);
      accO[dt] = __builtin_amdgcn_mfma_f32_16x16x32_bf16(pf, vf, accO[dt], 0, 0, 0);
    }
  }
#pragma unroll
  for (int j = 0; j < 4; ++j) {
    float inv = 1.f / l[j];
    long tok = 512 + q0 + w * 16 + lg * 4 + j;
#pragma unroll
    for (int dt = 0; dt < 8; ++dt) {
      long idx = tok * 3072 + h * 128 + dt * 16 + lr;
      OutTok[idx] = f2bf(bf2f(OutTok[idx]) + accO[dt][j] * inv);
    }
  }
}

// =====================================================================

extern "C" void kernel_launch(void* const* d_in, const int* in_sizes, int n_in,
                              void* d_out, int out_size, void* d_ws, size_t ws_size,
                              hipStream_t stream) {
  const float* hs    = (const float*)d_in[0];
  const float* ehs   = (const float*)d_in[1];
  const float* img   = (const float*)d_in[2];
  const float* Wq    = (const float*)d_in[3];
  const float* bq    = (const float*)d_in[4];
  const float* Wk    = (const float*)d_in[5];
  const float* bk    = (const float*)d_in[6];
  const float* Wv    = (const float*)d_in[7];
  const float* bv    = (const float*)d_in[8];
  const float* Waq   = (const float*)d_in[9];
  const float* baq   = (const float*)d_in[10];
  const float* Wak   = (const float*)d_in[11];
  const float* bak   = (const float*)d_in[12];
  const float* Wav   = (const float*)d_in[13];
  const float* bav   = (const float*)d_in[14];
  const float* Wo    = (const float*)d_in[15];
  const float* bo    = (const float*)d_in[16];
  const float* Wao   = (const float*)d_in[17];
  const float* bao   = (const float*)d_in[18];
  const float* Wkip  = (const float*)d_in[19];
  const float* Wvip  = (const float*)d_in[20];
  const float* lq_dn = (const float*)d_in[21];
  const float* lq_up = (const float*)d_in[22];
  const float* lk_dn = (const float*)d_in[23];
  const float* lk_up = (const float*)d_in[24];
  const float* lv_dn = (const float*)d_in[25];
  const float* lv_up = (const float*)d_in[26];
  const float* lp_dn = (const float*)d_in[27];
  const float* lp_up = (const float*)d_in[28];
  float* outp = (float*)d_out;

  char* ws = (char*)d_ws;
  size_t off = 0;
  auto take = [&](size_t b) { char* p = ws + off; off += (b + 255) & ~(size_t)255; return p; };
  u16*   WTb  = (u16*)take(9216LL * 3072 * 2);   // reused transposed-weight buffer
  u16*   hsb  = (u16*)take(2048LL * 3072 * 2);
  u16*   ehsb = (u16*)take(512LL * 3072 * 2);
  u16*   imgb = (u16*)take(64LL * 3072 * 2);
  float* P0   = (float*)take(2048LL * 3072 * 4); // proj scratch (later aliased by AttnTok)
  float* E0   = (float*)take(512LL * 9216 * 4);  // enc proj (later aliased by VT)
  float* IP0  = (float*)take(64LL * 6144 * 4);
  u16*   QBf  = (u16*)take(24LL * 2560 * 128 * 2);
  u16*   KBf  = (u16*)take(24LL * 2560 * 128 * 2);
  u16*   VBf  = (u16*)take(24LL * 2560 * 128 * 2);
  u16*   KipB = (u16*)take(24LL * 64 * 128 * 2);
  u16*   VipB = (u16*)take(24LL * 64 * 128 * 2);
  u16*   VipT = (u16*)take(24LL * 64 * 128 * 2);
  float* bpk  = (float*)take(9216 * 4);
  float* tl   = (float*)take(1024LL * 16 * 4);
  u16* VTf     = (u16*)E0;  // alias: E0 dead after enc rms passes
  u16* AttnTok = (u16*)P0;  // alias: P0 dead after v convert

  // 1. convert activations, pack enc bias
  cvt_bf16<<<3072, 256, 0, stream>>>(hs, hsb, 2048LL * 3072);
  cvt_bf16<<<768, 256, 0, stream>>>(ehs, ehsb, 512LL * 3072);
  cvt_bf16<<<96, 256, 0, stream>>>(img, imgb, 64LL * 3072);
  pack_bias<<<36, 256, 0, stream>>>(baq, bak, bav, bpk);

  // 2. encoder path: packed [Waq|Wak|Wav]
  {
    WTArgs a;
    a.src[0] = Waq; a.dst[0] = WTb;
    a.src[1] = Wak; a.dst[1] = WTb + 3072LL * 3072;
    a.src[2] = Wav; a.dst[2] = WTb + 2 * 3072LL * 3072;
    transpose_w<<<dim3(96, 96, 3), 256, 0, stream>>>(a);
  }
  gemm_bf16<128, 4, 4><<<dim3(4, 72), 256, 0, stream>>>(ehsb, 3072, WTb, 3072, E0, 9216, bpk, 3072);
  rms_heads<<<512, 256, 0, stream>>>(E0, 9216, QBf, 2560, 0, 1);
  rms_heads<<<512, 256, 0, stream>>>(E0 + 3072, 9216, KBf, 2560, 0, 1);
  rms_heads<<<512, 256, 0, stream>>>(E0 + 6144, 9216, VBf, 2560, 0, 0);

  // 3. IP projections: packed [Wkip|Wvip]
  {
    WTArgs a;
    a.src[0] = Wkip; a.dst[0] = WTb;
    a.src[1] = Wvip; a.dst[1] = WTb + 3072LL * 3072;
    a.src[2] = Wkip; a.dst[2] = WTb;  // unused (z=2)
    transpose_w<<<dim3(96, 96, 2), 256, 0, stream>>>(a);
  }
  gemm_bf16<64, 4, 2><<<dim3(1, 48), 256, 0, stream>>>(imgb, 3072, WTb, 3072, IP0, 6144, nullptr, 3072);
  rms_heads<<<64, 256, 0, stream>>>(IP0, 6144, KipB, 64, 0, 1);
  rms_heads<<<64, 256, 0, stream>>>(IP0 + 3072, 6144, VipB, 64, 0, 0);
  transpose_v<<<dim3(2, 4, 24), 256, 0, stream>>>(VipB, VipT, 64);

  // 4. main q/k/v: packed [Wq|Wk|Wv]
  {
    WTArgs a;
    a.src[0] = Wq; a.dst[0] = WTb;
    a.src[1] = Wk; a.dst[1] = WTb + 3072LL * 3072;
    a.src[2] = Wv; a.dst[2] = WTb + 2 * 3072LL * 3072;
    transpose_w<<<dim3(96, 96, 3), 256, 0, stream>>>(a);
  }
  // Q
  gemm_bf16<128, 4, 4><<<dim3(16, 24), 256, 0, stream>>>(hsb, 3072, WTb, 3072, P0, 3072, bq, 3072);
  lora_dn<<<1024, 256, 0, stream>>>(hs + 1024LL * 3072, 3072, lq_dn, tl);
  lora_up<<<1024, 256, 0, stream>>>(tl, lq_up, P0 + 1024LL * 3072, 3072);
  rms_heads<<<2048, 256, 0, stream>>>(P0, 3072, QBf, 2560, 512, 1);
  // K
  gemm_bf16<128, 4, 4><<<dim3(16, 24), 256, 0, stream>>>(hsb, 3072, WTb + 3072LL * 3072, 3072, P0, 3072, bk, 3072);
  lora_dn<<<1024, 256, 0, stream>>>(hs + 1024LL * 3072, 3072, lk_dn, tl);
  lora_up<<<1024, 256, 0, stream>>>(tl, lk_up, P0 + 1024LL * 3072, 3072);
  rms_heads<<<2048, 256, 0, stream>>>(P0, 3072, KBf, 2560, 512, 1);
  // V
  gemm_bf16<128, 4, 4><<<dim3(16, 24), 256, 0, stream>>>(hsb, 3072, WTb + 2 * 3072LL * 3072, 3072, P0, 3072, bv, 3072);
  lora_dn<<<1024, 256, 0, stream>>>(hs + 1024LL * 3072, 3072, lv_dn, tl);
  lora_up<<<1024, 256, 0, stream>>>(tl, lv_up, P0 + 1024LL * 3072, 3072);
  rms_heads<<<2048, 256, 0, stream>>>(P0, 3072, VBf, 2560, 512, 0);
  // V transpose for PV fragments
  transpose_v<<<dim3(80, 4, 24), 256, 0, stream>>>(VBf, VTf, 2560);

  // 5. attention
  attn_main<<<dim3(40, 24), 256, 0, stream>>>(QBf, KBf, VTf, AttnTok);
  attn_ip<<<dim3(32, 24), 256, 0, stream>>>(QBf, KipB, VipT, AttnTok);

  // 6. output projections: packed [Wao|Wo]
  {
    WTArgs a;
    a.src[0] = Wao; a.dst[0] = WTb;
    a.src[1] = Wo;  a.dst[1] = WTb + 3072LL * 3072;
    a.src[2] = Wao; a.dst[2] = WTb;  // unused (z=2)
    transpose_w<<<dim3(96, 96, 2), 256, 0, stream>>>(a);
  }
  gemm_bf16<128, 4, 4><<<dim3(4, 24), 256, 0, stream>>>(AttnTok, 3072, WTb, 3072, outp, 3072, bao, 3072);
  gemm_bf16<128, 4, 4><<<dim3(16, 24), 256, 0, stream>>>(AttnTok + 512LL * 3072, 3072, WTb + 3072LL * 3072, 3072,
                                                         outp + 512LL * 3072, 3072, bo, 3072);
  // 7. final LoRA on post-projection main (rows 1536.. of output)
  lora_dn<<<1024, 256, 0, stream>>>(outp + 1536LL * 3072, 3072, lp_dn, tl);
  lora_up<<<1024, 256, 0, stream>>>(tl, lp_up, outp + 1536LL * 3072, 3072);
}

// Round 2
// 807.684 us; speedup vs baseline: 1.1764x; 1.1764x over previous
//
#include <hip/hip_runtime.h>

typedef unsigned short u16;
typedef short s16x8 __attribute__((ext_vector_type(8)));
typedef float f32x4 __attribute__((ext_vector_type(4)));
typedef const __attribute__((address_space(1))) unsigned int* as1_u32p;
typedef __attribute__((address_space(3))) unsigned int* as3_u32p;

static_assert(sizeof(s16x8) == 16, "");

struct alignas(8) U16x4 { u16 x, y, z, w; };

__device__ __forceinline__ u16 f2bf(float f) {
  union { float f; unsigned u; } c; c.f = f;
  return (u16)((c.u + 0x7fffu + ((c.u >> 16) & 1u)) >> 16);
}
__device__ __forceinline__ float bf2f(u16 h) {
  union { unsigned u; float f; } c; c.u = ((unsigned)h) << 16;
  return c.f;
}
__device__ __forceinline__ void async16(const void* g, void* l) {
  __builtin_amdgcn_global_load_lds((as1_u32p)g, (as3_u32p)l, 16, 0, 0);
}

// ---------------- fp32 -> bf16 flat convert ----------------
__launch_bounds__(256)
__global__ void cvt_bf16(const float* __restrict__ in, u16* __restrict__ out, long n) {
  long i = ((long)blockIdx.x * 256 + threadIdx.x) * 8;
  if (i >= n) return;
  float4 a = *(const float4*)(in + i);
  float4 b = *(const float4*)(in + i + 4);
  U16x4 o0{f2bf(a.x), f2bf(a.y), f2bf(a.z), f2bf(a.w)};
  U16x4 o1{f2bf(b.x), f2bf(b.y), f2bf(b.z), f2bf(b.w)};
  *(U16x4*)(out + i) = o0;
  *(U16x4*)(out + i + 4) = o1;
}

// ---------------- pack 3 biases into one 9216 vector ----------------
__launch_bounds__(256)
__global__ void pack_bias(const float* __restrict__ a, const float* __restrict__ b,
                          const float* __restrict__ c, float* __restrict__ out) {
  int i = blockIdx.x * 256 + threadIdx.x;
  if (i >= 9216) return;
  out[i] = (i < 3072) ? a[i] : (i < 6144) ? b[i - 3072] : c[i - 6144];
}

// ---------------- weight transpose: W(K=3072,N=3072) f32 -> W^T(N,K) bf16 ----------------
struct WTArgs { const float* src[3]; u16* dst[3]; };

__launch_bounds__(256)
__global__ void transpose_w(WTArgs args) {
  const float* src = args.src[blockIdx.z];
  u16* dst = args.dst[blockIdx.z];
  __shared__ float tile[32][33];
  int k0 = blockIdx.x * 32, n0 = blockIdx.y * 32;
  int r = threadIdx.x >> 3, c4 = (threadIdx.x & 7) * 4;
  float4 v = *(const float4*)(src + (long)(k0 + r) * 3072 + n0 + c4);
  tile[r][c4 + 0] = v.x; tile[r][c4 + 1] = v.y;
  tile[r][c4 + 2] = v.z; tile[r][c4 + 3] = v.w;
  __syncthreads();
  U16x4 o{f2bf(tile[c4 + 0][r]), f2bf(tile[c4 + 1][r]),
          f2bf(tile[c4 + 2][r]), f2bf(tile[c4 + 3][r])};
  *(U16x4*)(dst + (long)(n0 + r) * 3072 + k0 + c4) = o;
}

// ---------------- bf16 head transpose (T,128)->(128,T) per head ----------------
__launch_bounds__(256)
__global__ void transpose_v(const u16* __restrict__ VB, u16* __restrict__ VT, int T) {
  __shared__ u16 tile[32][34];
  int h = blockIdx.z;
  int t0 = blockIdx.x * 32, d0 = blockIdx.y * 32;
  int r = threadIdx.x >> 3, c4 = (threadIdx.x & 7) * 4;
  U16x4 v = *(const U16x4*)(VB + ((long)h * T + t0 + r) * 128 + d0 + c4);
  tile[r][c4 + 0] = v.x; tile[r][c4 + 1] = v.y;
  tile[r][c4 + 2] = v.z; tile[r][c4 + 3] = v.w;
  __syncthreads();
  U16x4 o{tile[c4 + 0][r], tile[c4 + 1][r], tile[c4 + 2][r], tile[c4 + 3][r]};
  *(U16x4*)(VT + ((long)h * 128 + d0 + r) * T + t0 + c4) = o;
}

// ---------------- RMS + to_heads, fp32 input (IP path) ----------------
__launch_bounds__(256)
__global__ void rms_heads(const float* __restrict__ in, int ldin,
                          u16* __restrict__ out, int OT, int t0, int do_rms) {
  const int t = blockIdx.x;
  const int w = threadIdx.x >> 6, lane = threadIdx.x & 63;
#pragma unroll
  for (int hh = 0; hh < 6; ++hh) {
    int h = w * 6 + hh;
    const float* x = in + (long)t * ldin + h * 128 + lane * 2;
    float a = x[0], b = x[1];
    float scale = 1.f;
    if (do_rms) {
      float ss = a * a + b * b;
#pragma unroll
      for (int st = 1; st < 64; st <<= 1) ss += __shfl_xor(ss, st, 64);
      scale = rsqrtf(ss * (1.f / 128.f) + 1e-5f);
    }
    unsigned pa = f2bf(a * scale), pb = f2bf(b * scale);
    *(unsigned*)(out + ((long)h * OT + t0 + t) * 128 + lane * 2) = pa | (pb << 16);
  }
}

// ---------------- fused 3-way RMS/convert from fused (T,9216) bf16 projection ----------------
// segments: [0,3072)=Q (rms), [3072,6144)=K (rms), [6144,9216)=V (plain)
__launch_bounds__(256)
__global__ void rms3(const u16* __restrict__ in, u16* __restrict__ Qo,
                     u16* __restrict__ Ko, u16* __restrict__ Vo, int t0) {
  const int t = blockIdx.x;
  const int w = threadIdx.x >> 6, lane = threadIdx.x & 63;
#pragma unroll
  for (int seg = 0; seg < 3; ++seg) {
    u16* out = (seg == 0) ? Qo : (seg == 1) ? Ko : Vo;
#pragma unroll
    for (int hh = 0; hh < 6; ++hh) {
      int h = w * 6 + hh;
      unsigned pv = *(const unsigned*)(in + (long)t * 9216 + seg * 3072 + h * 128 + lane * 2);
      float a = bf2f((u16)(pv & 0xffff)), b = bf2f((u16)(pv >> 16));
      float scale = 1.f;
      if (seg < 2) {
        float ss = a * a + b * b;
#pragma unroll
        for (int st = 1; st < 64; st <<= 1) ss += __shfl_xor(ss, st, 64);
        scale = rsqrtf(ss * (1.f / 128.f) + 1e-5f);
      }
      unsigned pa = f2bf(a * scale), pb = f2bf(b * scale);
      *(unsigned*)(out + ((long)h * 2560 + t0 + t) * 128 + lane * 2) = pa | (pb << 16);
    }
  }
}

// ---------------- LoRA ----------------
__launch_bounds__(256)
__global__ void lora_dn(const float* __restrict__ X, int ldx,
                        const float* __restrict__ dn, float* __restrict__ t) {
  __shared__ float red[4][16];
  const int m = blockIdx.x;
  const float* xr = X + (long)m * ldx;
  float p[16];
#pragma unroll
  for (int r = 0; r < 16; ++r) p[r] = 0.f;
  for (int k = threadIdx.x; k < 3072; k += 256) {
    float a = xr[k];
    const float* d = dn + (long)k * 16;
#pragma unroll
    for (int r = 0; r < 16; ++r) p[r] += a * d[r];
  }
#pragma unroll
  for (int r = 0; r < 16; ++r)
#pragma unroll
    for (int st = 1; st < 64; st <<= 1) p[r] += __shfl_xor(p[r], st, 64);
  int lane = threadIdx.x & 63, w = threadIdx.x >> 6;
  if (lane == 0) {
#pragma unroll
    for (int r = 0; r < 16; ++r) red[w][r] = p[r];
  }
  __syncthreads();
  if (threadIdx.x < 16) {
    int r = threadIdx.x;
    t[(long)m * 16 + r] = red[0][r] + red[1][r] + red[2][r] + red[3][r];
  }
}

__launch_bounds__(256)
__global__ void lora_up(const float* __restrict__ t, const float* __restrict__ up,
                        float* __restrict__ Y, int ldy) {
  const int m = blockIdx.x;
  float tv[16];
#pragma unroll
  for (int r = 0; r < 16; ++r) tv[r] = t[(long)m * 16 + r];
  float* yr = Y + (long)m * ldy;
  for (int n = threadIdx.x; n < 3072; n += 256) {
    float a = 0.f;
#pragma unroll
    for (int r = 0; r < 16; ++r) a += tv[r] * up[(long)r * 3072 + n];
    yr[n] += a;
  }
}

__launch_bounds__(256)
__global__ void lora_up_bf(const float* __restrict__ t, const float* __restrict__ up,
                           u16* __restrict__ Y, int ldy) {
  const int m = blockIdx.x;
  float tv[16];
#pragma unroll
  for (int r = 0; r < 16; ++r) tv[r] = t[(long)m * 16 + r];
  u16* yr = Y + (long)m * ldy;
  for (int n = threadIdx.x; n < 3072; n += 256) {
    float a = 0.f;
#pragma unroll
    for (int r = 0; r < 16; ++r) a += tv[r] * up[(long)r * 3072 + n];
    yr[n] = f2bf(bf2f(yr[n]) + a);
  }
}

// ---------------- GEMM: C(M,N) = A(M,K)bf16 @ B^T(N,K)bf16 + bias ----------------
// 256 threads / 4 waves; BM x 128 tile; BK=64; XOR-swizzled LDS; global_load_lds.
// XCD-aware block swizzle (requires gridDim.x*gridDim.y % 8 == 0).
template <int BM, int MI, int NI, int OUTBF>
__launch_bounds__(256)
__global__ void gemm_bf16(const u16* __restrict__ A, int lda,
                          const u16* __restrict__ B, int ldb,
                          void* __restrict__ Cv, int ldc,
                          const float* __restrict__ bias, int K) {
  constexpr int WCOLS = 128 / (NI * 16);
  constexpr int ABYTES = BM * 128;
  __shared__ char smem[ABYTES + 128 * 128];
  char* As = smem;
  char* Bs = smem + ABYTES;
  const int tid = threadIdx.x;
  const int w = tid >> 6, lane = tid & 63;
  const int lr = lane & 15, lg = lane >> 4;
  const int wr = w / WCOLS, wc = w % WCOLS;
  // XCD swizzle (bijective since nwg % 8 == 0 at every call site)
  const int nbx = gridDim.x;
  const int nwg = nbx * gridDim.y;
  const int flat = blockIdx.y * nbx + blockIdx.x;
  const int swz = (flat & 7) * (nwg >> 3) + (flat >> 3);
  const long m0 = (long)(swz % nbx) * BM;
  const long n0 = (long)(swz / nbx) * 128;
  f32x4 acc[MI][NI] = {};
  constexpr int ACH = BM / 32;
  for (int kb = 0; kb < K; kb += 64) {
    __syncthreads();
#pragma unroll
    for (int i = 0; i < ACH; ++i) {
      int x = (tid + 256 * i) * 16;
      int row = x >> 7;
      int sx = x ^ ((row & 7) << 4);
      async16((const char*)(A + (m0 + row) * lda + kb) + (sx & 127),
              As + ((w << 10) + (i << 12)));
    }
#pragma unroll
    for (int i = 0; i < 4; ++i) {
      int x = (tid + 256 * i) * 16;
      int row = x >> 7;
      int sx = x ^ ((row & 7) << 4);
      async16((const char*)(B + (n0 + row) * ldb + kb) + (sx & 127),
              Bs + ((w << 10) + (i << 12)));
    }
    __syncthreads();
#pragma unroll
    for (int kc = 0; kc < 2; ++kc) {
      s16x8 af[MI], bfr[NI];
#pragma unroll
      for (int mi = 0; mi < MI; ++mi) {
        int row = wr * (MI * 16) + mi * 16 + lr;
        int b = ((row << 7) + kc * 64 + lg * 16) ^ ((row & 7) << 4);
        af[mi] = *(const s16x8*)(As + b);
      }
#pragma unroll
      for (int ni = 0; ni < NI; ++ni) {
        int row = wc * (NI * 16) + ni * 16 + lr;
        int b = ((row << 7) + kc * 64 + lg * 16) ^ ((row & 7) << 4);
        bfr[ni] = *(const s16x8*)(Bs + b);
      }
#pragma unroll
      for (int mi = 0; mi < MI; ++mi)
#pragma unroll
        for (int ni = 0; ni < NI; ++ni)
          acc[mi][ni] = __builtin_amdgcn_mfma_f32_16x16x32_bf16(af[mi], bfr[ni], acc[mi][ni], 0, 0, 0);
    }
  }
#pragma unroll
  for (int mi = 0; mi < MI; ++mi) {
#pragma unroll
    for (int ni = 0; ni < NI; ++ni) {
      long col = n0 + wc * (NI * 16) + ni * 16 + lr;
      float bv = bias ? bias[col] : 0.f;
#pragma unroll
      for (int j = 0; j < 4; ++j) {
        long row = m0 + wr * (MI * 16) + mi * 16 + lg * 4 + j;
        if (OUTBF)
          ((u16*)Cv)[row * ldc + col] = f2bf(acc[mi][ni][j] + bv);
        else
          ((float*)Cv)[row * ldc + col] = acc[mi][ni][j] + bv;
      }
    }
  }
}

// ---------------- main masked attention ----------------
// Static-max softmax: Q,K are RMS-normed so score*scale <= sqrt(128) ~= 11.32 < 12.
// p = exp(s*sc - 12); no running max, no rescale; l summed per-lane, reduced once.
// Double-buffered K/V tiles (one barrier per tile, prefetch overlaps compute).
__launch_bounds__(256)
__global__ void attn_main(const u16* __restrict__ QB, const u16* __restrict__ KB,
                          const u16* __restrict__ VT, u16* __restrict__ OutTok) {
  __shared__ char smem[73728];  // K[2]@16KB, V[2]@16KB, P 8KB
  const int tid = threadIdx.x, w = tid >> 6, lane = tid & 63;
  const int lr = lane & 15, lg = lane >> 4;
  const int h = blockIdx.y;
  const int q0 = blockIdx.x * 64;
  const u16* Qrow = QB + (long)(h * 2560 + q0 + w * 16 + lr) * 128;
  s16x8 qf[4];
#pragma unroll
  for (int dc = 0; dc < 4; ++dc) qf[dc] = *(const s16x8*)(Qrow + dc * 32 + lg * 8);
  f32x4 accO[8] = {};
  float l_r[4] = {0.f, 0.f, 0.f, 0.f};
  const int kv0 = (q0 >= 1536) ? 1536 : 0;
  const float sc = 0.08838834764831845f;

  auto stage = [&](int kv, int buf) {
#pragma unroll
    for (int i = 0; i < 4; ++i) {  // K tile: 64 rows x 256B
      int x = (tid + 256 * i) * 16;
      int row = x >> 8;
      int sx = x ^ ((row & 7) << 4);
      async16((const char*)(KB + (long)(h * 2560 + kv + row) * 128) + (sx & 255),
              smem + buf * 16384 + ((w << 10) + (i << 12)));
    }
#pragma unroll
    for (int i = 0; i < 4; ++i) {  // V^T tile: 128 rows x 128B
      int x = (tid + 256 * i) * 16;
      int row = x >> 7;
      int sx = x ^ ((row & 7) << 4);
      async16((const char*)(VT + (long)(h * 128 + row) * 2560 + kv) + (sx & 127),
              smem + 32768 + buf * 16384 + ((w << 10) + (i << 12)));
    }
  };

  stage(kv0, 0);
  __syncthreads();
  int cur = 0;
  for (int kv = kv0; kv < 2560; kv += 64) {
    if (kv + 64 < 2560) stage(kv + 64, cur ^ 1);
    const char* Ks = smem + cur * 16384;
    const char* Vs = smem + 32768 + cur * 16384;
    char* Pw = smem + 65536 + w * 2048;
    f32x4 s[4] = {};
#pragma unroll
    for (int kt = 0; kt < 4; ++kt)
#pragma unroll
      for (int dc = 0; dc < 4; ++dc) {
        int row = kt * 16 + lr;
        int b = ((row << 8) + dc * 64 + lg * 16) ^ ((row & 7) << 4);
        s16x8 kf = *(const s16x8*)(Ks + b);
        s[kt] = __builtin_amdgcn_mfma_f32_16x16x32_bf16(qf[dc], kf, s[kt], 0, 0, 0);
      }
#pragma unroll
    for (int kt = 0; kt < 4; ++kt)
#pragma unroll
      for (int j = 0; j < 4; ++j) {
        float pv = __expf(fmaf(s[kt][j], sc, -12.0f));
        l_r[j] += pv;
        int prow = lg * 4 + j;
        int b = ((prow << 7) + (kt * 16 + lr) * 2) ^ ((prow & 7) << 4);
        *(u16*)(Pw + b) = f2bf(pv);
      }
    asm volatile("s_waitcnt lgkmcnt(0)" ::: "memory");
#pragma unroll
    for (int kc = 0; kc < 2; ++kc) {
      int pb = ((lr << 7) + kc * 64 + lg * 16) ^ ((lr & 7) << 4);
      s16x8 pf = *(const s16x8*)(Pw + pb);
#pragma unroll
      for (int dt = 0; dt < 8; ++dt) {
        int row = dt * 16 + lr;
        int b = ((row << 7) + kc * 64 + lg * 16) ^ ((row & 7) << 4);
        s16x8 vf = *(const s16x8*)(Vs + b);
        accO[dt] = __builtin_amdgcn_mfma_f32_16x16x32_bf16(pf, vf, accO[dt], 0, 0, 0);
      }
    }
    __syncthreads();
    cur ^= 1;
  }
#pragma unroll
  for (int j = 0; j < 4; ++j)
#pragma unroll
    for (int st = 1; st < 16; st <<= 1) l_r[j] += __shfl_xor(l_r[j], st, 16);
#pragma unroll
  for (int j = 0; j < 4; ++j) {
    float inv = 1.f / l_r[j];
    long tok = q0 + w * 16 + lg * 4 + j;
#pragma unroll
    for (int dt = 0; dt < 8; ++dt) {
      long col = h * 128 + dt * 16 + lr;
      OutTok[tok * 3072 + col] = f2bf(accO[dt][j] * inv);
    }
  }
}

// ---------------- IP attention (64 keys), static-max, adds into OutTok rows 512.. ----------------
__launch_bounds__(256)
__global__ void attn_ip(const u16* __restrict__ QB, const u16* __restrict__ KipB,
                        const u16* __restrict__ VipT, u16* __restrict__ OutTok) {
  __shared__ char smem[40960];
  char* Ks = smem;
  char* Vs = smem + 16384;
  char* Ps = smem + 32768;
  const int tid = threadIdx.x, w = tid >> 6, lane = tid & 63;
  const int lr = lane & 15, lg = lane >> 4;
  const int h = blockIdx.y;
  const int q0 = blockIdx.x * 64;
  const u16* Qrow = QB + (long)(h * 2560 + 512 + q0 + w * 16 + lr) * 128;
  s16x8 qf[4];
#pragma unroll
  for (int dc = 0; dc < 4; ++dc) qf[dc] = *(const s16x8*)(Qrow + dc * 32 + lg * 8);
#pragma unroll
  for (int i = 0; i < 4; ++i) {
    int x = (tid + 256 * i) * 16;
    int row = x >> 8;
    int sx = x ^ ((row & 7) << 4);
    async16((const char*)(KipB + (long)(h * 64 + row) * 128) + (sx & 255),
            Ks + ((w << 10) + (i << 12)));
  }
#pragma unroll
  for (int i = 0; i < 4; ++i) {
    int x = (tid + 256 * i) * 16;
    int row = x >> 7;
    int sx = x ^ ((row & 7) << 4);
    async16((const char*)(VipT + (long)(h * 128 + row) * 64) + (sx & 127),
            Vs + ((w << 10) + (i << 12)));
  }
  __syncthreads();
  const float sc = 0.08838834764831845f;
  f32x4 s[4] = {};
#pragma unroll
  for (int kt = 0; kt < 4; ++kt)
#pragma unroll
    for (int dc = 0; dc < 4; ++dc) {
      int row = kt * 16 + lr;
      int b = ((row << 8) + dc * 64 + lg * 16) ^ ((row & 7) << 4);
      s16x8 kf = *(const s16x8*)(Ks + b);
      s[kt] = __builtin_amdgcn_mfma_f32_16x16x32_bf16(qf[dc], kf, s[kt], 0, 0, 0);
    }
  float l[4] = {0.f, 0.f, 0.f, 0.f}, p[4][4];
#pragma unroll
  for (int kt = 0; kt < 4; ++kt)
#pragma unroll
    for (int j = 0; j < 4; ++j) {
      float pv = __expf(fmaf(s[kt][j], sc, -12.0f));
      p[kt][j] = pv;
      l[j] += pv;
    }
#pragma unroll
  for (int j = 0; j < 4; ++j)
#pragma unroll
    for (int st = 1; st < 16; st <<= 1) l[j] += __shfl_xor(l[j], st, 16);
  char* Pw = Ps + w * 2048;
#pragma unroll
  for (int kt = 0; kt < 4; ++kt)
#pragma unroll
    for (int j = 0; j < 4; ++j) {
      int row = lg * 4 + j;
      int b = ((row << 7) + (kt * 16 + lr) * 2) ^ ((row & 7) << 4);
      *(u16*)(Pw + b) = f2bf(p[kt][j]);
    }
  asm volatile("s_waitcnt lgkmcnt(0)" ::: "memory");
  f32x4 accO[8] = {};
#pragma unroll
  for (int kc = 0; kc < 2; ++kc) {
    int pb = ((lr << 7) + kc * 64 + lg * 16) ^ ((lr & 7) << 4);
    s16x8 pf = *(const s16x8*)(Pw + pb);
#pragma unroll
    for (int dt = 0; dt < 8; ++dt) {
      int row = dt * 16 + lr;
      int b = ((row << 7) + kc * 64 + lg * 16) ^ ((row & 7) << 4);
      s16x8 vf = *(const s16x8*)(Vs + b);
      accO[dt] = __builtin_amdgcn_mfma_f32_16x16x32_bf16(pf, vf, accO[dt], 0, 0, 0);
    }
  }
#pragma unroll
  for (int j = 0; j < 4; ++j) {
    float inv = 1.f / l[j];
    long tok = 512 + q0 + w * 16 + lg * 4 + j;
#pragma unroll
    for (int dt = 0; dt < 8; ++dt) {
      long idx = tok * 3072 + h * 128 + dt * 16 + lr;
      OutTok[idx] = f2bf(bf2f(OutTok[idx]) + accO[dt][j] * inv);
    }
  }
}

// =====================================================================

extern "C" void kernel_launch(void* const* d_in, const int* in_sizes, int n_in,
                              void* d_out, int out_size, void* d_ws, size_t ws_size,
                              hipStream_t stream) {
  const float* hs    = (const float*)d_in[0];
  const float* ehs   = (const float*)d_in[1];
  const float* img   = (const float*)d_in[2];
  const float* Wq    = (const float*)d_in[3];
  const float* bq    = (const float*)d_in[4];
  const float* Wk    = (const float*)d_in[5];
  const float* bk    = (const float*)d_in[6];
  const float* Wv    = (const float*)d_in[7];
  const float* bv    = (const float*)d_in[8];
  const float* Waq   = (const float*)d_in[9];
  const float* baq   = (const float*)d_in[10];
  const float* Wak   = (const float*)d_in[11];
  const float* bak   = (const float*)d_in[12];
  const float* Wav   = (const float*)d_in[13];
  const float* bav   = (const float*)d_in[14];
  const float* Wo    = (const float*)d_in[15];
  const float* bo    = (const float*)d_in[16];
  const float* Wao   = (const float*)d_in[17];
  const float* bao   = (const float*)d_in[18];
  const float* Wkip  = (const float*)d_in[19];
  const float* Wvip  = (const float*)d_in[20];
  const float* lq_dn = (const float*)d_in[21];
  const float* lq_up = (const float*)d_in[22];
  const float* lk_dn = (const float*)d_in[23];
  const float* lk_up = (const float*)d_in[24];
  const float* lv_dn = (const float*)d_in[25];
  const float* lv_up = (const float*)d_in[26];
  const float* lp_dn = (const float*)d_in[27];
  const float* lp_up = (const float*)d_in[28];
  float* outp = (float*)d_out;

  char* ws = (char*)d_ws;
  size_t off = 0;
  auto take = [&](size_t b) { char* p = ws + off; off += (b + 255) & ~(size_t)255; return p; };
  u16*   WTb  = (u16*)take(9216LL * 3072 * 2);   // transposed-weight buffer (reused)
  u16*   hsb  = (u16*)take(2048LL * 3072 * 2);
  u16*   ehsb = (u16*)take(512LL * 3072 * 2);
  u16*   imgb = (u16*)take(64LL * 3072 * 2);
  u16*   P0b  = (u16*)take(2048LL * 9216 * 2);   // fused qkv projection (bf16); also VTf/AttnTok later
  float* IP0  = (float*)take(64LL * 6144 * 4);
  u16*   QBf  = (u16*)take(24LL * 2560 * 128 * 2);
  u16*   KBf  = (u16*)take(24LL * 2560 * 128 * 2);
  u16*   VBf  = (u16*)take(24LL * 2560 * 128 * 2);
  u16*   KipB = (u16*)take(24LL * 64 * 128 * 2);
  u16*   VipB = (u16*)take(24LL * 64 * 128 * 2);
  u16*   VipT = (u16*)take(24LL * 64 * 128 * 2);
  float* bpk  = (float*)take(9216 * 4);
  float* tl   = (float*)take(1024LL * 16 * 4);
  u16* VTf     = P0b;                                   // alias (P0b dead after rms3 main)
  u16* AttnTok = (u16*)((char*)P0b + (16u << 20));      // alias, 16MB past VTf

  // 1. convert activations
  cvt_bf16<<<3072, 256, 0, stream>>>(hs, hsb, 2048LL * 3072);
  cvt_bf16<<<768, 256, 0, stream>>>(ehs, ehsb, 512LL * 3072);
  cvt_bf16<<<96, 256, 0, stream>>>(img, imgb, 64LL * 3072);
  pack_bias<<<36, 256, 0, stream>>>(baq, bak, bav, bpk);

  // 2. encoder path: packed [Waq|Wak|Wav], fused N=9216 GEMM -> bf16
  {
    WTArgs a;
    a.src[0] = Waq; a.dst[0] = WTb;
    a.src[1] = Wak; a.dst[1] = WTb + 3072LL * 3072;
    a.src[2] = Wav; a.dst[2] = WTb + 2 * 3072LL * 3072;
    transpose_w<<<dim3(96, 96, 3), 256, 0, stream>>>(a);
  }
  gemm_bf16<128, 4, 4, 1><<<dim3(4, 72), 256, 0, stream>>>(ehsb, 3072, WTb, 3072, P0b, 9216, bpk, 3072);
  rms3<<<512, 256, 0, stream>>>(P0b, QBf, KBf, VBf, 0);

  // 3. IP projections: packed [Wkip|Wvip]
  {
    WTArgs a;
    a.src[0] = Wkip; a.dst[0] = WTb;
    a.src[1] = Wvip; a.dst[1] = WTb + 3072LL * 3072;
    a.src[2] = Wkip; a.dst[2] = WTb;  // unused
    transpose_w<<<dim3(96, 96, 2), 256, 0, stream>>>(a);
  }
  gemm_bf16<64, 4, 2, 0><<<dim3(1, 48), 256, 0, stream>>>(imgb, 3072, WTb, 3072, IP0, 6144, nullptr, 3072);
  rms_heads<<<64, 256, 0, stream>>>(IP0, 6144, KipB, 64, 0, 1);
  rms_heads<<<64, 256, 0, stream>>>(IP0 + 3072, 6144, VipB, 64, 0, 0);
  transpose_v<<<dim3(2, 4, 24), 256, 0, stream>>>(VipB, VipT, 64);

  // 4. main q/k/v: packed [Wq|Wk|Wv], ONE fused N=9216 GEMM
  {
    WTArgs a;
    a.src[0] = Wq; a.dst[0] = WTb;
    a.src[1] = Wk; a.dst[1] = WTb + 3072LL * 3072;
    a.src[2] = Wv; a.dst[2] = WTb + 2 * 3072LL * 3072;
    transpose_w<<<dim3(96, 96, 3), 256, 0, stream>>>(a);
  }
  pack_bias<<<36, 256, 0, stream>>>(bq, bk, bv, bpk);
  gemm_bf16<128, 4, 4, 1><<<dim3(16, 72), 256, 0, stream>>>(hsb, 3072, WTb, 3072, P0b, 9216, bpk, 3072);
  // LoRAs add into the fused projection (rows 1024.., per-segment columns)
  lora_dn<<<1024, 256, 0, stream>>>(hs + 1024LL * 3072, 3072, lq_dn, tl);
  lora_up_bf<<<1024, 256, 0, stream>>>(tl, lq_up, P0b + 1024LL * 9216, 9216);
  lora_dn<<<1024, 256, 0, stream>>>(hs + 1024LL * 3072, 3072, lk_dn, tl);
  lora_up_bf<<<1024, 256, 0, stream>>>(tl, lk_up, P0b + 1024LL * 9216 + 3072, 9216);
  lora_dn<<<1024, 256, 0, stream>>>(hs + 1024LL * 3072, 3072, lv_dn, tl);
  lora_up_bf<<<1024, 256, 0, stream>>>(tl, lv_up, P0b + 1024LL * 9216 + 6144, 9216);
  rms3<<<2048, 256, 0, stream>>>(P0b, QBf, KBf, VBf, 512);
  // V transpose for PV fragments (VTf aliases P0b, now dead)
  transpose_v<<<dim3(80, 4, 24), 256, 0, stream>>>(VBf, VTf, 2560);

  // 5. attention
  attn_main<<<dim3(40, 24), 256, 0, stream>>>(QBf, KBf, VTf, AttnTok);
  attn_ip<<<dim3(32, 24), 256, 0, stream>>>(QBf, KipB, VipT, AttnTok);

  // 6. output projections: packed [Wao|Wo]
  {
    WTArgs a;
    a.src[0] = Wao; a.dst[0] = WTb;
    a.src[1] = Wo;  a.dst[1] = WTb + 3072LL * 3072;
    a.src[2] = Wao; a.dst[2] = WTb;  // unused
    transpose_w<<<dim3(96, 96, 2), 256, 0, stream>>>(a);
  }
  gemm_bf16<128, 4, 4, 0><<<dim3(4, 24), 256, 0, stream>>>(AttnTok, 3072, WTb, 3072, outp, 3072, bao, 3072);
  gemm_bf16<128, 4, 4, 0><<<dim3(16, 24), 256, 0, stream>>>(AttnTok + 512LL * 3072, 3072, WTb + 3072LL * 3072, 3072,
                                                            outp + 512LL * 3072, 3072, bo, 3072);
  // 7. final LoRA on post-projection main (rows 1536.. of output)
  lora_dn<<<1024, 256, 0, stream>>>(outp + 1536LL * 3072, 3072, lp_dn, tl);
  lora_up<<<1024, 256, 0, stream>>>(tl, lp_up, outp + 1536LL * 3072, 3072);
}